// Round 7
// baseline (58.284 us; speedup 1.0000x reference)
//
#include <hip/hip_runtime.h>
#include <math.h>

// Problem constants (fixed by harness)
#define BB   32
#define LL   8192
#define CC   32
#define NTOK 1023      // (L-16)/8 + 1
#define KK   16
#define HID  32

__device__ __forceinline__ float4 f4add(float4 a, float4 b) {
    return make_float4(a.x + b.x, a.y + b.y, a.z + b.z, a.w + b.w);
}
__device__ __forceinline__ float4 f4fma(float4 a, float4 b, float4 c) {
    return make_float4(fmaf(a.x, b.x, c.x), fmaf(a.y, b.y, c.y),
                       fmaf(a.z, b.z, c.z), fmaf(a.w, b.w, c.w));
}
__device__ __forceinline__ float4 shflx4(float4 v, int m) {
    return make_float4(__shfl_xor(v.x, m, 64), __shfl_xor(v.y, m, 64),
                       __shfl_xor(v.z, m, 64), __shfl_xor(v.w, m, 64));
}

// ---------------- Fused stats + alpha kernel ----------------
// Blocks 0..1023   : stats — (b,s-slice of 256 rows), register partials,
//                    token stats via 8KB LDS partials, smem 9.5KB.
// Blocks 1024..3071: alpha MLP — (b, 16-token tile) x 32 ch -> [b][n][c].
//   FIX vs r5/r6: ff loads are UNCONDITIONAL (n clamped; only the store is
//   masked) and issued BEFORE the w1->LDS staging. The conditional loads made
//   the compiler drop f0/f1 from registers (VGPR_Count=32 < the 32 floats of
//   f alone, no spill traffic -> it re-loaded ff inside the j-loop; both
//   branched rounds sat at ~43us while the unconditional round-3 version ran
//   ~12us). launch_bounds(256,2) gives the allocator up to 128 VGPRs.
__global__ void __launch_bounds__(256, 2)
k_fused(const float* __restrict__ x, const float* __restrict__ ff,
        const float* __restrict__ w1, const float* __restrict__ b1,
        const float* __restrict__ w2, const float* __restrict__ b2,
        float* __restrict__ ps, float* __restrict__ pq,
        float* __restrict__ mu_l, float* __restrict__ rstd_l,
        float* __restrict__ alpha_t) {
    __shared__ float4 smem4[592];          // 9472 B, union of both parts
    int t = threadIdx.x;

    if (blockIdx.x < 1024) {
        // ================= stats part =================
        float4* part_s = smem4;            // [32 rgrp][8 c4]
        float4* part_q = part_s + 256;
        float4* halo_s = part_q + 256;     // [8 c4]
        float4* halo_q = halo_s + 8;
        float4* wred_s = halo_q + 8;       // [4 wave][8 c4]
        float4* wred_q = wred_s + 32;

        int b  = blockIdx.x >> 5;
        int s  = blockIdx.x & 31;
        int c4 = t & 7, rgrp = t >> 3;
        const float4* xb = (const float4*)x + ((size_t)b * LL + s * 256) * 8;

        // 8 rows x 4 channels in registers (8 loads in flight)
        float4 v[8];
#pragma unroll
        for (int k = 0; k < 8; ++k)
            v[k] = xb[(rgrp * 8 + k) * 8 + c4];
        float4 s4 = make_float4(0.f, 0.f, 0.f, 0.f);
        float4 q4 = make_float4(0.f, 0.f, 0.f, 0.f);
#pragma unroll
        for (int k = 0; k < 8; ++k) {
            s4 = f4add(s4, v[k]);
            q4 = f4fma(v[k], v[k], q4);
        }
        part_s[t] = s4;                    // t == rgrp*8 + c4
        part_q[t] = q4;

        // halo: 8 rows after the slice (wave 0 only; zeros for s==31)
        if (t < 64) {
            float4 hs = make_float4(0.f, 0.f, 0.f, 0.f);
            float4 hq = make_float4(0.f, 0.f, 0.f, 0.f);
            if (s < 31) {
                float4 hv = xb[(256 + (t >> 3)) * 8 + c4];
                hs = hv; hq = f4fma(hv, hv, hq);
            }
            hs = f4add(hs, shflx4(hs, 8));  hq = f4add(hq, shflx4(hq, 8));
            hs = f4add(hs, shflx4(hs, 16)); hq = f4add(hq, shflx4(hq, 16));
            hs = f4add(hs, shflx4(hs, 32)); hq = f4add(hq, shflx4(hq, 32));
            if (t < 8) { halo_s[t] = hs; halo_q[t] = hq; }
        }

        // global partials: reduce over rgrp bits (3,4,5 in-wave, then waves)
        float4 gs = s4, gq = q4;
        gs = f4add(gs, shflx4(gs, 8));  gq = f4add(gq, shflx4(gq, 8));
        gs = f4add(gs, shflx4(gs, 16)); gq = f4add(gq, shflx4(gq, 16));
        gs = f4add(gs, shflx4(gs, 32)); gq = f4add(gq, shflx4(gq, 32));
        if ((t & 56) == 0) {               // one lane per (wave, c4)
            wred_s[(t >> 6) * 8 + c4] = gs;
            wred_q[(t >> 6) * 8 + c4] = gq;
        }
        __syncthreads();

        // token stats: token nl = t>>3 needs rgrps nl and nl+1 (32 = halo)
        int nl = t >> 3;
        int n  = s * 32 + nl;
        if (n < NTOK) {
            float4 a  = (nl < 31) ? part_s[(nl + 1) * 8 + c4] : halo_s[c4];
            float4 bq = (nl < 31) ? part_q[(nl + 1) * 8 + c4] : halo_q[c4];
            float4 ts = f4add(part_s[t], a);
            float4 tq = f4add(part_q[t], bq);
            float4 mu = make_float4(ts.x * 0.0625f, ts.y * 0.0625f,
                                    ts.z * 0.0625f, ts.w * 0.0625f);
            float4 var;
            var.x = fmaxf(fmaf(-mu.x, mu.x, tq.x * 0.0625f), 1e-4f);
            var.y = fmaxf(fmaf(-mu.y, mu.y, tq.y * 0.0625f), 1e-4f);
            var.z = fmaxf(fmaf(-mu.z, mu.z, tq.z * 0.0625f), 1e-4f);
            var.w = fmaxf(fmaf(-mu.w, mu.w, tq.w * 0.0625f), 1e-4f);
            float4 rs = make_float4(1.f / sqrtf(var.x), 1.f / sqrtf(var.y),
                                    1.f / sqrtf(var.z), 1.f / sqrtf(var.w));
            size_t o = (size_t)(b * NTOK + n) * 8 + c4;
            ((float4*)mu_l)[o]   = mu;
            ((float4*)rstd_l)[o] = rs;
        }

        // finish global partial write (one float4 per c4)
        if (t < 8) {
            float4 a = f4add(f4add(wred_s[t], wred_s[8 + t]),
                             f4add(wred_s[16 + t], wred_s[24 + t]));
            float4 c = f4add(f4add(wred_q[t], wred_q[8 + t]),
                             f4add(wred_q[16 + t], wred_q[24 + t]));
            ((float4*)ps)[blockIdx.x * 8 + t] = a;
            ((float4*)pq)[blockIdx.x * 8 + t] = c;
        }
    } else {
        // ================= alpha part =================
        float*  smem = (float*)smem4;
        float*  w1t  = smem;                   // [32][16] transposed w1
        float2* bw   = (float2*)(smem + 512);  // (b1[j], w2[j])
        float*  b2s  = smem + 576;
        float*  als  = smem + 580;             // [32][17] alpha tile (padded)
        int rel  = blockIdx.x - 1024;
        int b    = rel >> 6;
        int n0   = (rel & 63) * 16;

        int c0 = t >> 4, c1 = c0 + 16, nl = t & 15;
        int n  = min(n0 + nl, NTOK - 1);       // clamp: loads ALWAYS execute

        // issue ff loads FIRST (HBM latency hides under the w1 staging below)
        const float4* p0 = (const float4*)(ff + ((size_t)(b * CC + c0) * NTOK + n) * KK);
        const float4* p1 = (const float4*)(ff + ((size_t)(b * CC + c1) * NTOK + n) * KK);
        float4 fv0[4], fv1[4];
#pragma unroll
        for (int v = 0; v < 4; ++v) fv0[v] = p0[v];
#pragma unroll
        for (int v = 0; v < 4; ++v) fv1[v] = p1[v];

        for (int i = t; i < KK * HID; i += 256) {
            int j = i >> 4, k = i & 15;
            w1t[i] = w1[k * HID + j];
        }
        if (t < HID) bw[t] = make_float2(b1[t], w2[t]);
        if (t == 0)  b2s[0] = b2[0];
        __syncthreads();

        float f0[KK], f1[KK];
#pragma unroll
        for (int v = 0; v < 4; ++v) {
            f0[4*v] = fv0[v].x; f0[4*v+1] = fv0[v].y;
            f0[4*v+2] = fv0[v].z; f0[4*v+3] = fv0[v].w;
            f1[4*v] = fv1[v].x; f1[4*v+1] = fv1[v].y;
            f1[4*v+2] = fv1[v].z; f1[4*v+3] = fv1[v].w;
        }

        const float C0 = -2.302211325f;    // -1.5957691216 * log2(e)
        const float C1 = -0.102943702f;    // -0.0713548162 * log2(e)
        float out0 = b2s[0], out1 = b2s[0];
        const float4* w1t4 = (const float4*)w1t;
#pragma unroll
        for (int j = 0; j < HID; ++j) {
            float2 bwj = bw[j];
            float h0 = bwj.x, h1 = bwj.x;
#pragma unroll
            for (int q = 0; q < 4; ++q) {
                float4 w = w1t4[j * 4 + q];
                h0 = fmaf(f0[4*q  ], w.x, h0); h1 = fmaf(f1[4*q  ], w.x, h1);
                h0 = fmaf(f0[4*q+1], w.y, h0); h1 = fmaf(f1[4*q+1], w.y, h1);
                h0 = fmaf(f0[4*q+2], w.z, h0); h1 = fmaf(f1[4*q+2], w.z, h1);
                h0 = fmaf(f0[4*q+3], w.w, h0); h1 = fmaf(f1[4*q+3], w.w, h1);
            }
            float t0 = h0 * h0,            t1 = h1 * h1;
            float a0 = fmaf(t0, C1, C0),   a1 = fmaf(t1, C1, C0);
            float e0 = exp2f(a0 * h0),     e1 = exp2f(a1 * h1);
            float g0 = h0 * __builtin_amdgcn_rcpf(1.0f + e0);
            float g1 = h1 * __builtin_amdgcn_rcpf(1.0f + e1);
            out0 = fmaf(g0, bwj.y, out0);
            out1 = fmaf(g1, bwj.y, out1);
        }
        als[c0 * 17 + nl] = __builtin_amdgcn_rcpf(1.0f + exp2f(-1.44269504f * out0));
        als[c1 * 17 + nl] = __builtin_amdgcn_rcpf(1.0f + exp2f(-1.44269504f * out1));
        __syncthreads();

        // coalesced [b][n][c] write: 512 contiguous floats, float2 per thread
        int flat = t * 2;
        int nn = flat >> 5, cc = flat & 31;
        if (n0 + nn < NTOK) {
            float2 o;
            o.x = als[cc * 17 + nn];
            o.y = als[(cc + 1) * 17 + nn];
            *(float2*)(alpha_t + ((size_t)(b * NTOK + n0 + nn)) * CC + cc) = o;
        }
    }
}

// ---------------- K1b: finish global stats (reduce 32 slices) ----------------
__global__ void k1b_final(const float* __restrict__ ps, const float* __restrict__ pq,
                          float* __restrict__ mu_g, float* __restrict__ rstd_g) {
    int t = threadIdx.x;           // t = b*32 + c
    int b = t >> 5, c = t & 31;
    float s = 0.f, q = 0.f;
#pragma unroll 8
    for (int sl = 0; sl < 32; ++sl) {
        s += ps[(b * 32 + sl) * 32 + c];
        q += pq[(b * 32 + sl) * 32 + c];
    }
    float mu  = s * (1.0f / LL);
    float var = fmaxf(q * (1.0f / LL) - mu * mu, 1e-4f);
    mu_g[t]   = mu;
    rstd_g[t] = 1.0f / sqrtf(var);
}

// ---------------- K4: fused normalize + mix + affine (float4) ----------------
__global__ void k4_main(const float4* __restrict__ x4,
                        const float4* __restrict__ mug4, const float4* __restrict__ rsg4,
                        const float4* __restrict__ mul4, const float4* __restrict__ rsl4,
                        const float4* __restrict__ al4,
                        const float4* __restrict__ sc4, const float4* __restrict__ bi4,
                        float4* __restrict__ out4) {
    int i4 = blockIdx.x * 256 + threadIdx.x;
    int c4 = i4 & 7;
    int l  = (i4 >> 3) & (LL - 1);
    int b  = i4 >> 16;                  // L*C/4 = 65536
    int n  = (l >= 5) ? min((l - 5) >> 3, NTOK - 1) : 0;

    float4 xv = x4[i4];
    int g4 = b * 8 + c4;
    float4 mg = mug4[g4], rg = rsg4[g4];
    int o4 = (b * NTOK + n) * 8 + c4;
    float4 ml = mul4[o4], rl = rsl4[o4], av = al4[o4];
    float4 s  = sc4[c4],  bi = bi4[c4];

    float4 y;
    {
        float xg = fminf(fmaxf((xv.x - mg.x) * rg.x, -30.f), 30.f);
        float xl = fminf(fmaxf((xv.x - ml.x) * rl.x, -30.f), 30.f);
        y.x = fmaf(av.x, xl - xg, xg) * s.x + bi.x;
    }
    {
        float xg = fminf(fmaxf((xv.y - mg.y) * rg.y, -30.f), 30.f);
        float xl = fminf(fmaxf((xv.y - ml.y) * rl.y, -30.f), 30.f);
        y.y = fmaf(av.y, xl - xg, xg) * s.y + bi.y;
    }
    {
        float xg = fminf(fmaxf((xv.z - mg.z) * rg.z, -30.f), 30.f);
        float xl = fminf(fmaxf((xv.z - ml.z) * rl.z, -30.f), 30.f);
        y.z = fmaf(av.z, xl - xg, xg) * s.z + bi.z;
    }
    {
        float xg = fminf(fmaxf((xv.w - mg.w) * rg.w, -30.f), 30.f);
        float xl = fminf(fmaxf((xv.w - ml.w) * rl.w, -30.f), 30.f);
        y.w = fmaf(av.w, xl - xg, xg) * s.w + bi.w;
    }
    out4[i4] = y;
}

extern "C" void kernel_launch(void* const* d_in, const int* in_sizes, int n_in,
                              void* d_out, int out_size, void* d_ws, size_t ws_size,
                              hipStream_t stream) {
    const float* x    = (const float*)d_in[0];
    const float* ff   = (const float*)d_in[1];
    const float* aw1  = (const float*)d_in[2];
    const float* ab1  = (const float*)d_in[3];
    const float* aw2  = (const float*)d_in[4];
    const float* ab2  = (const float*)d_in[5];
    // d_in[6..9] = beta weights: dead code in the reference output
    const float* scal = (const float*)d_in[10];
    const float* bias = (const float*)d_in[11];
    float* out = (float*)d_out;

    float* wsf     = (float*)d_ws;
    float* ps      = wsf;                        //   32768 ((b,s,c))
    float* pq      = wsf + 32768;                //   32768
    float* mu_g    = wsf + 65536;                //    1024
    float* rstd_g  = wsf + 66560;                //    1024
    float* mu_l    = wsf + 67584;                // 1047552
    float* rstd_l  = mu_l    + 1047552;          // 1047552
    float* alpha_t = rstd_l  + 1047552;          // 1047552  ([b][n][c])
    // total 3,210,240 floats = 12.25 MB of d_ws

    k_fused<<<3072, 256, 0, stream>>>(x, ff, aw1, ab1, aw2, ab2,
                                      ps, pq, mu_l, rstd_l, alpha_t);
    k1b_final<<<1, 1024, 0, stream>>>(ps, pq, mu_g, rstd_g);
    k4_main<<<8192, 256, 0, stream>>>((const float4*)x,
                                      (const float4*)mu_g, (const float4*)rstd_g,
                                      (const float4*)mu_l, (const float4*)rstd_l,
                                      (const float4*)alpha_t,
                                      (const float4*)scal, (const float4*)bias,
                                      (float4*)out);
}